// Round 11
// baseline (231.146 us; speedup 1.0000x reference)
//
#include <hip/hip_runtime.h>

#define NB 4
#define CIN 8
#define CO 16
#define NV 100000
#define NVP 100096           // NV rounded to 128
#define NM 98304
#define NPOS (NM*8)          // 786432 = 1024*768
#define NBLK ((NV+255)/256)  // 391
#define VPW 14               // vertices per wave in k_reduce
#define REDB 1786            // k_reduce blocks (grid must match!)

typedef short s16x8 __attribute__((ext_vector_type(8)));
typedef float f32x4 __attribute__((ext_vector_type(4)));
typedef unsigned short u16;
typedef unsigned int u32;

// ---- ws layout (bytes, 128-aligned) ----
#define OFF_STAT  800256                 // float stat[96]: BN1 sum16/sq16, BN2 sum16/sq16
#define OFF_ROWS  800640                 // int row_start[NV]
#define OFF_BSUM  1200768                // int bsum[NBLK]
#define OFF_SLOT  1202432                // int slot[NPOS]
#define OFF_XTB   4348160                // bf16 xtb[NV][32]  ([v][b*8+c])
#define OFF_W1B   10748160               // bf16 w1[128][64]
#define OFF_W2B   10764544               // bf16 w2[128][128]
#define OFF_MBUF  23597312               // bf16 mbuf[NV][4][16] (means, 12.8 MB)
#define OFF_HBUF  49197312               // bf16 hbuf[NPOS][16col][4b] (128B rows)
#define OFF_CNTR  149860608              // int cntR[8][NVP] (3.2 MB, zeroed by k_xt)
#define OFF_BASER (OFF_CNTR + 8*NVP*4)   // int baseR[8][NVP]
#define WS_NEED   (OFF_BASER + 8*NVP*4)  // 156,266,752

static __device__ __forceinline__ u16 f2bf(float f){
  union { float f; u32 u; } v; v.f = f;
  u32 r = v.u + 0x7fffu + ((v.u >> 16) & 1u);
  return (u16)(r >> 16);
}
static __device__ __forceinline__ float bf2f_lo(u32 w){
  union { u32 u; float f; } v; v.u = w << 16; return v.f;
}
static __device__ __forceinline__ float bf2f_hi(u32 w){
  union { u32 u; float f; } v; v.u = w & 0xffff0000u; return v.f;
}
static __device__ __forceinline__ float bf2f16(u16 h){
  union { u32 u; float f; } v; v.u = ((u32)h) << 16; return v.f;
}
static __device__ __forceinline__ u32 pk2(float a, float b){
  return (u32)f2bf(a) | (((u32)f2bf(b)) << 16);
}

// ---------- xt: transpose x -> xtb bf16 | tails: W->bf16 + stat zero + cntR zero ----------
// grid MUST be NBLK + 8 blocks x 256
__global__ __launch_bounds__(256) void k_xt(const float* __restrict__ x, u16* __restrict__ xtb,
    const float* __restrict__ W1, const float* __restrict__ W2,
    u16* __restrict__ w1b, u16* __restrict__ w2b, float* __restrict__ stat,
    int* __restrict__ cntR)
{
  __shared__ float tile[32][257];
  if (blockIdx.x >= NBLK){
    int b3 = blockIdx.x - NBLK;
    if (b3 == 0 && threadIdx.x < 64) stat[threadIdx.x] = 0.f;
    const int T1 = 128*64, T2 = T1 + 128*128;
    for (int i = b3*256 + threadIdx.x; i < T2; i += 8*256){
      if (i < T1) w1b[i] = f2bf(W1[i]);
      else { int j = i - T1; w2b[j] = f2bf(W2[j]); }
    }
    // zero the 8 replica counters (3.2 MB)
    int4 z = {0,0,0,0};
    int4* c4 = (int4*)cntR;
    const int NC4 = (8*NVP*4)/16;   // 200192
    for (int q = b3*256 + threadIdx.x; q < NC4; q += 8*256) c4[q] = z;
    return;
  }
  int t = threadIdx.x;
  int v0 = blockIdx.x*256;
  #pragma unroll
  for (int r = 0; r < 32; r++){
    int v = v0 + t;
    tile[r][t] = (v < NV) ? x[(size_t)r*NV + v] : 0.f;
  }
  __syncthreads();
  int v = v0 + t;
  if (v < NV){
    u16 o[32] __attribute__((aligned(16)));
    #pragma unroll
    for (int r = 0; r < 32; r++) o[r] = f2bf(tile[r][t]);
    uint4* dst = (uint4*)(xtb + (size_t)v*32);
    #pragma unroll
    for (int k = 0; k < 4; k++) dst[k] = *(uint4*)(o + k*8);
  }
}

// ---------- slot: ONE atomic pass, XCD-replicated counters ----------
// grid MUST be 1024 blocks x 256. Block b uses replica b&7.
__global__ __launch_bounds__(256) void k_slot(const int* __restrict__ elem,
    int* __restrict__ cntR, int* __restrict__ slot)
{
  int b = blockIdx.x;
  int* myc = cntR + (b & 7)*NVP;
  int i0 = b*768 + threadIdx.x;
  #pragma unroll
  for (int k = 0; k < 3; k++){
    int i = i0 + k*256;
    int v = elem[i];
    slot[i] = atomicAdd(myc + v, 1);
  }
}

// ---------- scan stage A: per-block raw sums over the 8 replicas ----------
__global__ __launch_bounds__(256) void k_scan_a(const int* __restrict__ cntR, int* __restrict__ bsum)
{
  int v = blockIdx.x*256 + threadIdx.x;
  int x = 0;
  if (v < NV){
    #pragma unroll
    for (int r = 0; r < 8; r++) x += cntR[r*NVP + v];
  }
  #pragma unroll
  for (int off = 32; off > 0; off >>= 1) x += __shfl_down(x, off);
  __shared__ int ls[4];
  int wid = threadIdx.x >> 6, lane = threadIdx.x & 63;
  if (lane == 0) ls[wid] = x;
  __syncthreads();
  if (threadIdx.x == 0) bsum[blockIdx.x] = ls[0] + ls[1] + ls[2] + ls[3];
}

// ---------- scan stage C: rows + per-replica bases ----------
__global__ __launch_bounds__(256) void k_scan_c(const int* __restrict__ cntR,
    const int* __restrict__ bsum, int* __restrict__ rows, int* __restrict__ baseR)
{
  int wid = threadIdx.x >> 6, lane = threadIdx.x & 63;
  int v = blockIdx.x*256 + threadIdx.x;
  int cr[8];
  #pragma unroll
  for (int r = 0; r < 8; r++) cr[r] = (v < NV) ? cntR[r*NVP + v] : 0;
  int pre[8]; int x = 0;
  #pragma unroll
  for (int r = 0; r < 8; r++){ pre[r] = x; x += cr[r]; }
  int incl = x;
  #pragma unroll
  for (int off = 1; off <= 32; off <<= 1){
    int y = __shfl_up(incl, off);
    if (lane >= off) incl += y;
  }
  __shared__ int wt[4];
  __shared__ int sbase;
  if (lane == 63) wt[wid] = incl;
  if (threadIdx.x < 64){
    int s = 0;
    for (int i = threadIdx.x; i < blockIdx.x; i += 64) s += bsum[i];
    #pragma unroll
    for (int off = 32; off > 0; off >>= 1) s += __shfl_down(s, off);
    if (threadIdx.x == 0) sbase = s;
  }
  __syncthreads();
  int woff = 0;
  for (int w = 0; w < 4; w++) if (w < wid) woff += wt[w];
  if (v < NV){
    int row0 = sbase + woff + incl - x;
    rows[v] = row0;
    #pragma unroll
    for (int r = 0; r < 8; r++) baseR[r*NVP + v] = row0 + pre[r];
  }
}

// ---------- conv1: 2 groups/wave straight-line, W1 in regs, inline pos from slot+baseR ----------
// grid MUST be 3072 blocks x 256 (12288 waves; ngrp = 24576)
__global__ __launch_bounds__(256) void k_conv1(const int* __restrict__ elem,
    const u16* __restrict__ xtb, const u16* __restrict__ w1b,
    const float* __restrict__ b1, const int* __restrict__ slot,
    const int* __restrict__ baseR, u16* __restrict__ hbuf)
{
  const int lane = threadIdx.x & 63;
  const int col = lane & 15, kg = lane >> 4, b = lane & 3;
  s16x8 wf[8][2];
  #pragma unroll
  for (int j2 = 0; j2 < 8; j2++)
    #pragma unroll
    for (int t = 0; t < 2; t++)
      wf[j2][t] = *(const s16x8*)(w1b + (j2*16 + col)*64 + t*32 + kg*8);
  float bb[8];
  #pragma unroll
  for (int j2 = 0; j2 < 8; j2++) bb[j2] = b1[j2*16 + col];

  int wave = (int)((blockIdx.x*blockDim.x + threadIdx.x) >> 6);
  int g0 = wave, g1 = wave + 12288;
  int ma0 = g0*4 + (col >> 2), ma1 = g1*4 + (col >> 2);
  int me0 = g0*4 + kg,         me1 = g1*4 + kg;

  int e00 = elem[ma0*8 + kg], e01 = elem[ma0*8 + 4 + kg];
  int e10 = elem[ma1*8 + kg], e11 = elem[ma1*8 + 4 + kg];
  int4 s0l = *(const int4*)(slot + me0*8), s0h = *(const int4*)(slot + me0*8 + 4);
  int4 s1l = *(const int4*)(slot + me1*8), s1h = *(const int4*)(slot + me1*8 + 4);
  int4 E0l = *(const int4*)(elem + me0*8), E0h = *(const int4*)(elem + me0*8 + 4);
  int4 E1l = *(const int4*)(elem + me1*8), E1h = *(const int4*)(elem + me1*8 + 4);
  s16x8 a00 = *(const s16x8*)(xtb + (size_t)e00*32 + b*8);
  s16x8 a01 = *(const s16x8*)(xtb + (size_t)e01*32 + b*8);
  s16x8 a10 = *(const s16x8*)(xtb + (size_t)e10*32 + b*8);
  s16x8 a11 = *(const s16x8*)(xtb + (size_t)e11*32 + b*8);

  const int* br0 = baseR + (((me0/96) & 7)*NVP);
  const int* br1 = baseR + (((me1/96) & 7)*NVP);
  int pe0[8], pe1[8];
  pe0[0] = br0[E0l.x] + s0l.x; pe0[1] = br0[E0l.y] + s0l.y;
  pe0[2] = br0[E0l.z] + s0l.z; pe0[3] = br0[E0l.w] + s0l.w;
  pe0[4] = br0[E0h.x] + s0h.x; pe0[5] = br0[E0h.y] + s0h.y;
  pe0[6] = br0[E0h.z] + s0h.z; pe0[7] = br0[E0h.w] + s0h.w;
  pe1[0] = br1[E1l.x] + s1l.x; pe1[1] = br1[E1l.y] + s1l.y;
  pe1[2] = br1[E1l.z] + s1l.z; pe1[3] = br1[E1l.w] + s1l.w;
  pe1[4] = br1[E1h.x] + s1h.x; pe1[5] = br1[E1h.y] + s1h.y;
  pe1[6] = br1[E1h.z] + s1h.z; pe1[7] = br1[E1h.w] + s1h.w;

  #pragma unroll
  for (int j2 = 0; j2 < 8; j2++){
    f32x4 c = {0.f,0.f,0.f,0.f};
    c = __builtin_amdgcn_mfma_f32_16x16x32_bf16(a00, wf[j2][0], c, 0, 0, 0);
    c = __builtin_amdgcn_mfma_f32_16x16x32_bf16(a01, wf[j2][1], c, 0, 0, 0);
    uint2 d; d.x = pk2(c[0]+bb[j2], c[1]+bb[j2]); d.y = pk2(c[2]+bb[j2], c[3]+bb[j2]);
    *(uint2*)(hbuf + (size_t)pe0[j2]*64 + col*4) = d;
  }
  #pragma unroll
  for (int j2 = 0; j2 < 8; j2++){
    f32x4 c = {0.f,0.f,0.f,0.f};
    c = __builtin_amdgcn_mfma_f32_16x16x32_bf16(a10, wf[j2][0], c, 0, 0, 0);
    c = __builtin_amdgcn_mfma_f32_16x16x32_bf16(a11, wf[j2][1], c, 0, 0, 0);
    uint2 d; d.x = pk2(c[0]+bb[j2], c[1]+bb[j2]); d.y = pk2(c[2]+bb[j2], c[3]+bb[j2]);
    *(uint2*)(hbuf + (size_t)pe1[j2]*64 + col*4) = d;
  }
}

// ---------- conv2: mbuf gather + BN1+relu inline, W2 in LDS, inline pos ----------
// grid MUST be 3072 blocks x 256
__global__ __launch_bounds__(256) void k_conv2(const int* __restrict__ elem,
    const u16* __restrict__ mbuf, const u16* __restrict__ w2b,
    const float* __restrict__ b2, const float* __restrict__ stat,
    const float* __restrict__ gamma, const float* __restrict__ beta,
    const int* __restrict__ slot, const int* __restrict__ baseR, u16* __restrict__ hbuf)
{
  __shared__ u16 wl[16384];   // 32 frags x 64 lanes x 8 bf16, chunk (j2*4+t)*64+lane
  __shared__ float sc[16], sh[16];
  #pragma unroll
  for (int r = 0; r < 8; r++){
    int q = threadIdx.x + 256*r;
    int j2t = q >> 6, ln = q & 63;
    int cc = ln & 15, kk = ln >> 4;
    int j2 = j2t >> 2, tt = j2t & 3;
    *(s16x8*)(wl + (size_t)q*8) =
        *(const s16x8*)(w2b + (j2*16 + cc)*128 + tt*32 + kk*8);
  }
  if (threadIdx.x < 16){
    int co = threadIdx.x;
    const float invn = 1.0f / (float)(NB*NV);
    float m = stat[co]*invn;
    float var = stat[16+co]*invn - m*m;
    float s = gamma[co]*rsqrtf(var + 1e-5f);
    sc[co] = s; sh[co] = beta[co] - m*s;
  }

  const int lane = threadIdx.x & 63;
  const int col = lane & 15, kg = lane >> 4, b = lane & 3;
  const int p = kg >> 1;            // slot parity
  const int c0 = (kg & 1)*8;        // channel offset
  float bb[8];
  #pragma unroll
  for (int j2 = 0; j2 < 8; j2++) bb[j2] = b2[j2*16 + col];

  int wave = (int)((blockIdx.x*blockDim.x + threadIdx.x) >> 6);
  int g0 = wave, g1 = wave + 12288;
  int ma0 = g0*4 + (col >> 2), ma1 = g1*4 + (col >> 2);
  int me0 = g0*4 + kg,         me1 = g1*4 + kg;

  int4 e0l = *(const int4*)(elem + ma0*8), e0h = *(const int4*)(elem + ma0*8 + 4);
  int4 e1l = *(const int4*)(elem + ma1*8), e1h = *(const int4*)(elem + ma1*8 + 4);
  int4 s0l = *(const int4*)(slot + me0*8), s0h = *(const int4*)(slot + me0*8 + 4);
  int4 s1l = *(const int4*)(slot + me1*8), s1h = *(const int4*)(slot + me1*8 + 4);
  int4 E0l = *(const int4*)(elem + me0*8), E0h = *(const int4*)(elem + me0*8 + 4);
  int4 E1l = *(const int4*)(elem + me1*8), E1h = *(const int4*)(elem + me1*8 + 4);

  int v00 = p ? e0l.y : e0l.x, v01 = p ? e0l.w : e0l.z;
  int v02 = p ? e0h.y : e0h.x, v03 = p ? e0h.w : e0h.z;
  int v10 = p ? e1l.y : e1l.x, v11 = p ? e1l.w : e1l.z;
  int v12 = p ? e1h.y : e1h.x, v13 = p ? e1h.w : e1h.z;

  s16x8 af0[4], af1[4];
  af0[0] = *(const s16x8*)(mbuf + (size_t)v00*64 + b*16 + c0);
  af0[1] = *(const s16x8*)(mbuf + (size_t)v01*64 + b*16 + c0);
  af0[2] = *(const s16x8*)(mbuf + (size_t)v02*64 + b*16 + c0);
  af0[3] = *(const s16x8*)(mbuf + (size_t)v03*64 + b*16 + c0);
  af1[0] = *(const s16x8*)(mbuf + (size_t)v10*64 + b*16 + c0);
  af1[1] = *(const s16x8*)(mbuf + (size_t)v11*64 + b*16 + c0);
  af1[2] = *(const s16x8*)(mbuf + (size_t)v12*64 + b*16 + c0);
  af1[3] = *(const s16x8*)(mbuf + (size_t)v13*64 + b*16 + c0);

  const int* br0 = baseR + (((me0/96) & 7)*NVP);
  const int* br1 = baseR + (((me1/96) & 7)*NVP);
  int pe0[8], pe1[8];
  pe0[0] = br0[E0l.x] + s0l.x; pe0[1] = br0[E0l.y] + s0l.y;
  pe0[2] = br0[E0l.z] + s0l.z; pe0[3] = br0[E0l.w] + s0l.w;
  pe0[4] = br0[E0h.x] + s0h.x; pe0[5] = br0[E0h.y] + s0h.y;
  pe0[6] = br0[E0h.z] + s0h.z; pe0[7] = br0[E0h.w] + s0h.w;
  pe1[0] = br1[E1l.x] + s1l.x; pe1[1] = br1[E1l.y] + s1l.y;
  pe1[2] = br1[E1l.z] + s1l.z; pe1[3] = br1[E1l.w] + s1l.w;
  pe1[4] = br1[E1h.x] + s1h.x; pe1[5] = br1[E1h.y] + s1h.y;
  pe1[6] = br1[E1h.z] + s1h.z; pe1[7] = br1[E1h.w] + s1h.w;

  __syncthreads();   // wl + sc/sh visible

  // BN1 + relu on gathered fragments (identical arithmetic to old k_apply1)
  #pragma unroll
  for (int t = 0; t < 4; t++){
    u32 r0[4], r1[4];
    #pragma unroll
    for (int ii = 0; ii < 4; ii++){
      int ca = c0 + 2*ii, cb = ca + 1;
      float x0 = bf2f16((u16)af0[t][2*ii])   * sc[ca] + sh[ca];
      float x1 = bf2f16((u16)af0[t][2*ii+1]) * sc[cb] + sh[cb];
      float y0 = bf2f16((u16)af1[t][2*ii])   * sc[ca] + sh[ca];
      float y1 = bf2f16((u16)af1[t][2*ii+1]) * sc[cb] + sh[cb];
      r0[ii] = pk2(fmaxf(x0, 0.f), fmaxf(x1, 0.f));
      r1[ii] = pk2(fmaxf(y0, 0.f), fmaxf(y1, 0.f));
    }
    af0[t] = *(s16x8*)r0;
    af1[t] = *(s16x8*)r1;
  }

  #pragma unroll
  for (int j2 = 0; j2 < 8; j2++){
    s16x8 w0 = *(const s16x8*)(wl + ((size_t)(j2*4 + 0)*64 + lane)*8);
    s16x8 w1 = *(const s16x8*)(wl + ((size_t)(j2*4 + 1)*64 + lane)*8);
    s16x8 w2 = *(const s16x8*)(wl + ((size_t)(j2*4 + 2)*64 + lane)*8);
    s16x8 w3 = *(const s16x8*)(wl + ((size_t)(j2*4 + 3)*64 + lane)*8);
    f32x4 c = {0.f,0.f,0.f,0.f};
    c = __builtin_amdgcn_mfma_f32_16x16x32_bf16(af0[0], w0, c, 0, 0, 0);
    c = __builtin_amdgcn_mfma_f32_16x16x32_bf16(af0[1], w1, c, 0, 0, 0);
    c = __builtin_amdgcn_mfma_f32_16x16x32_bf16(af0[2], w2, c, 0, 0, 0);
    c = __builtin_amdgcn_mfma_f32_16x16x32_bf16(af0[3], w3, c, 0, 0, 0);
    uint2 d; d.x = pk2(c[0]+bb[j2], c[1]+bb[j2]); d.y = pk2(c[2]+bb[j2], c[3]+bb[j2]);
    *(uint2*)(hbuf + (size_t)pe0[j2]*64 + col*4) = d;
  }
  #pragma unroll
  for (int j2 = 0; j2 < 8; j2++){
    s16x8 w0 = *(const s16x8*)(wl + ((size_t)(j2*4 + 0)*64 + lane)*8);
    s16x8 w1 = *(const s16x8*)(wl + ((size_t)(j2*4 + 1)*64 + lane)*8);
    s16x8 w2 = *(const s16x8*)(wl + ((size_t)(j2*4 + 2)*64 + lane)*8);
    s16x8 w3 = *(const s16x8*)(wl + ((size_t)(j2*4 + 3)*64 + lane)*8);
    f32x4 c = {0.f,0.f,0.f,0.f};
    c = __builtin_amdgcn_mfma_f32_16x16x32_bf16(af1[0], w0, c, 0, 0, 0);
    c = __builtin_amdgcn_mfma_f32_16x16x32_bf16(af1[1], w1, c, 0, 0, 0);
    c = __builtin_amdgcn_mfma_f32_16x16x32_bf16(af1[2], w2, c, 0, 0, 0);
    c = __builtin_amdgcn_mfma_f32_16x16x32_bf16(af1[3], w3, c, 0, 0, 0);
    uint2 d; d.x = pk2(c[0]+bb[j2], c[1]+bb[j2]); d.y = pk2(c[2]+bb[j2], c[3]+bb[j2]);
    *(uint2*)(hbuf + (size_t)pe1[j2]*64 + col*4) = d;
  }
}

// ---------- segmented reduce: 3 upfront row-groups (covers cnt<=12), half-wave/vertex ----------
// grid MUST be REDB blocks x 256
__global__ __launch_bounds__(256) void k_reduce(const u16* __restrict__ hbuf,
    const int* __restrict__ rows, u16* __restrict__ mbuf, float* __restrict__ stat)
{
  int lane = threadIdx.x & 63, wid = threadIdx.x >> 6;
  int half = lane >> 5;
  int hl   = lane & 31;
  int k8   = lane & 7;
  int rg   = (lane >> 3) & 3;
  int w = (blockIdx.x*blockDim.x + threadIdx.x) >> 6;
  int v0 = w * VPW;

  int vv = v0 + lane;
  int rr = 0;
  if (lane < VPW + 1) rr = (vv < NV) ? rows[vv] : NPOS;

  int rs[7], ce[7];
  #pragma unroll
  for (int j = 0; j < 7; j++){
    rs[j] = __shfl(rr, 2*j + half);
    ce[j] = __shfl(rr, 2*j + half + 1) - rs[j];
  }

  uint4 d0[7], d1[7], d2[7];
  #pragma unroll
  for (int j = 0; j < 7; j++){
    uint4 z = {0u,0u,0u,0u};
    d0[j] = z; d1[j] = z; d2[j] = z;
    const u16* base = hbuf + (size_t)rs[j]*64 + hl*8;
    if (rg     < ce[j]) d0[j] = *(const uint4*)(base);
    if (4 + rg < ce[j]) d1[j] = *(const uint4*)(base + 4*64);
    if (8 + rg < ce[j]) d2[j] = *(const uint4*)(base + 8*64);
  }

  float st_s0 = 0.f, st_q0 = 0.f, st_s1 = 0.f, st_q1 = 0.f;

  #pragma unroll
  for (int j = 0; j < 7; j++){
    float a0,a1,a2,a3,a4,a5,a6,a7;
    {
      uint4 dA = d0[j], dB = d1[j], dC = d2[j];
      a0 = bf2f_lo(dA.x)+bf2f_lo(dB.x)+bf2f_lo(dC.x);
      a1 = bf2f_hi(dA.x)+bf2f_hi(dB.x)+bf2f_hi(dC.x);
      a2 = bf2f_lo(dA.y)+bf2f_lo(dB.y)+bf2f_lo(dC.y);
      a3 = bf2f_hi(dA.y)+bf2f_hi(dB.y)+bf2f_hi(dC.y);
      a4 = bf2f_lo(dA.z)+bf2f_lo(dB.z)+bf2f_lo(dC.z);
      a5 = bf2f_hi(dA.z)+bf2f_hi(dB.z)+bf2f_hi(dC.z);
      a6 = bf2f_lo(dA.w)+bf2f_lo(dB.w)+bf2f_lo(dC.w);
      a7 = bf2f_hi(dA.w)+bf2f_hi(dB.w)+bf2f_hi(dC.w);
    }
    for (int p = 12; p < ce[j]; p += 4){
      uint4 d = {0u,0u,0u,0u};
      if (p + rg < ce[j]) d = *(const uint4*)(hbuf + (size_t)(rs[j]+p)*64 + hl*8);
      a0 += bf2f_lo(d.x); a1 += bf2f_hi(d.x); a2 += bf2f_lo(d.y); a3 += bf2f_hi(d.y);
      a4 += bf2f_lo(d.z); a5 += bf2f_hi(d.z); a6 += bf2f_lo(d.w); a7 += bf2f_hi(d.w);
    }
    #pragma unroll
    for (int off = 8; off <= 16; off <<= 1){
      a0 += __shfl_xor(a0, off); a1 += __shfl_xor(a1, off);
      a2 += __shfl_xor(a2, off); a3 += __shfl_xor(a3, off);
      a4 += __shfl_xor(a4, off); a5 += __shfl_xor(a5, off);
      a6 += __shfl_xor(a6, off); a7 += __shfl_xor(a7, off);
    }
    int v = v0 + 2*j + half;
    if (hl < 8 && v < NV){
      float inv = 1.0f / fmaxf((float)ce[j], 1.0f);
      float c0b[4] = {a0*inv, a1*inv, a2*inv, a3*inv};
      float c1b[4] = {a4*inv, a5*inv, a6*inv, a7*inv};
      #pragma unroll
      for (int q = 0; q < 4; q++){
        *(u32*)(mbuf + (size_t)v*64 + q*16 + 2*k8) = pk2(c0b[q], c1b[q]);
        st_s0 += c0b[q]; st_q0 += c0b[q]*c0b[q];
        st_s1 += c1b[q]; st_q1 += c1b[q]*c1b[q];
      }
    }
  }

  st_s0 += __shfl_xor(st_s0, 32); st_q0 += __shfl_xor(st_q0, 32);
  st_s1 += __shfl_xor(st_s1, 32); st_q1 += __shfl_xor(st_q1, 32);
  __shared__ float ls[4][16], lq[4][16];
  if (lane < 8){
    ls[wid][2*k8] = st_s0; ls[wid][2*k8+1] = st_s1;
    lq[wid][2*k8] = st_q0; lq[wid][2*k8+1] = st_q1;
  }
  __syncthreads();
  if (threadIdx.x < 32){
    int c2 = threadIdx.x & 15, which = threadIdx.x >> 4;
    float tot = 0.f;
    #pragma unroll
    for (int w2 = 0; w2 < 4; w2++) tot += which ? lq[w2][c2] : ls[w2][c2];
    unsafeAtomicAdd(stat + which*16 + c2, tot);
  }
}

// ---------- final: BN2 (inline finalize) + skip GEMV + relu + transpose ----------
__global__ __launch_bounds__(256) void k_final(const u16* __restrict__ mbuf,
    const float* __restrict__ stat, const float* __restrict__ gamma,
    const float* __restrict__ beta, const float* __restrict__ x,
    const float* __restrict__ wsk, const float* __restrict__ bsk, float* __restrict__ out)
{
  __shared__ float sc[16], sh[16];
  if (threadIdx.x < 16){
    int co = threadIdx.x;
    const float invn = 1.0f / (float)(NB*NV);
    float m = stat[co]*invn;
    float var = stat[16+co]*invn - m*m;
    float s = gamma[co]*rsqrtf(var + 1e-5f);
    sc[co] = s; sh[co] = beta[co] - m*s + bsk[co];
  }
  __syncthreads();
  int n = blockIdx.x*blockDim.x + threadIdx.x;
  int b = blockIdx.y;
  if (n >= NV) return;
  float xv[8];
  #pragma unroll
  for (int c = 0; c < 8; c++) xv[c] = x[((size_t)b*8 + c)*NV + n];
  const uint4* src = (const uint4*)(mbuf + (size_t)n*64 + b*16);
  uint4 m0 = src[0], m1 = src[1];
  u32 mw[8] = {m0.x,m0.y,m0.z,m0.w,m1.x,m1.y,m1.z,m1.w};
  #pragma unroll
  for (int k = 0; k < 8; k++){
    #pragma unroll
    for (int h = 0; h < 2; h++){
      int co = 2*k + h;
      float val = (h ? bf2f_hi(mw[k]) : bf2f_lo(mw[k]))*sc[co] + sh[co];
      #pragma unroll
      for (int c = 0; c < 8; c++) val += wsk[co*8+c]*xv[c];
      out[((size_t)b*16 + co)*NV + n] = fmaxf(val, 0.f);
    }
  }
}

extern "C" void kernel_launch(void* const* d_in, const int* in_sizes, int n_in,
                              void* d_out, int out_size, void* d_ws, size_t ws_size,
                              hipStream_t stream) {
  const float* x    = (const float*)d_in[0];
  const int*   elem = (const int*)  d_in[1];
  const float* W1   = (const float*)d_in[2];
  const float* b1   = (const float*)d_in[3];
  const float* g1   = (const float*)d_in[4];
  const float* be1  = (const float*)d_in[5];
  const float* W2   = (const float*)d_in[6];
  const float* b2   = (const float*)d_in[7];
  const float* g2   = (const float*)d_in[8];
  const float* be2  = (const float*)d_in[9];
  const float* Wsk  = (const float*)d_in[10];
  const float* bsk  = (const float*)d_in[11];
  float* out = (float*)d_out;

  if (ws_size < (size_t)WS_NEED) return;  // visible failure rather than corruption

  char* ws = (char*)d_ws;
  float* stat  = (float*)(ws + OFF_STAT);   // [0..31] BN1, [32..63] BN2
  int*   rows  = (int*)  (ws + OFF_ROWS);
  int*   bsum  = (int*)  (ws + OFF_BSUM);
  int*   slot  = (int*)  (ws + OFF_SLOT);
  u16*   xtb   = (u16*)  (ws + OFF_XTB);
  u16*   w1b   = (u16*)  (ws + OFF_W1B);
  u16*   w2b   = (u16*)  (ws + OFF_W2B);
  u16*   mbuf  = (u16*)  (ws + OFF_MBUF);
  u16*   hbuf  = (u16*)  (ws + OFF_HBUF);
  int*   cntR  = (int*)  (ws + OFF_CNTR);
  int*   baseR = (int*)  (ws + OFF_BASER);

  k_xt<<<NBLK + 8, 256, 0, stream>>>(x, xtb, W1, W2, w1b, w2b, stat, cntR);
  k_slot<<<1024, 256, 0, stream>>>(elem, cntR, slot);
  k_scan_a<<<NBLK, 256, 0, stream>>>(cntR, bsum);
  k_scan_c<<<NBLK, 256, 0, stream>>>(cntR, bsum, rows, baseR);

  k_conv1<<<3072, 256, 0, stream>>>(elem, xtb, w1b, b1, slot, baseR, hbuf);
  k_reduce<<<REDB, 256, 0, stream>>>(hbuf, rows, mbuf, stat);

  k_conv2<<<3072, 256, 0, stream>>>(elem, mbuf, w2b, b2, stat, g1, be1, slot, baseR, hbuf);
  k_reduce<<<REDB, 256, 0, stream>>>(hbuf, rows, mbuf, stat + 32);
  k_final<<<dim3((NV+255)/256, NB), 256, 0, stream>>>(mbuf, stat + 32, g2, be2, x, Wsk, bsk, out);
}

// Round 12
// 224.098 us; speedup vs baseline: 1.0315x; 1.0315x over previous
//
#include <hip/hip_runtime.h>

#define NB 4
#define CIN 8
#define CO 16
#define NV 100000
#define NVP 100096           // NV rounded to 128
#define NM 98304
#define NPOS (NM*8)          // 786432 = 1024*768
#define NBLK ((NV+255)/256)  // 391
#define VPW 14               // vertices per wave in k_reduce
#define REDB 1786            // k_reduce blocks (grid must match!)

typedef short s16x8 __attribute__((ext_vector_type(8)));
typedef float f32x4 __attribute__((ext_vector_type(4)));
typedef unsigned short u16;
typedef unsigned int u32;

// ---- ws layout (bytes, 128-aligned) ----
#define OFF_STAT  800256                 // float stat[96]: BN1 sum16/sq16, BN2 sum16/sq16
#define OFF_ROWS  800640                 // int row_start[NV]
#define OFF_BSUM  1200768                // int bsum[NBLK]
#define OFF_POS   1202432                // int slot[NPOS] -> pos[NPOS] (in-place)
#define OFF_XTB   4348160                // bf16 xtb[NV][32]  ([v][b*8+c])
#define OFF_W1B   10748160               // bf16 w1[128][64]
#define OFF_W2B   10764544               // bf16 w2[128][128]
#define OFF_MBUF  23597312               // bf16 mbuf[NV][4][16] (means, 12.8 MB)
#define OFF_HBUF  49197312               // bf16 hbuf[NPOS][16col][4b] (128B rows)
#define OFF_CNTR  149860608              // int cntR[8][NVP] (3.2 MB, zeroed by k_xt)
#define OFF_BASER (OFF_CNTR + 8*NVP*4)   // int baseR[8][NVP]
#define WS_NEED   (OFF_BASER + 8*NVP*4)  // 156,266,752

static __device__ __forceinline__ u16 f2bf(float f){
  union { float f; u32 u; } v; v.f = f;
  u32 r = v.u + 0x7fffu + ((v.u >> 16) & 1u);
  return (u16)(r >> 16);
}
static __device__ __forceinline__ float bf2f_lo(u32 w){
  union { u32 u; float f; } v; v.u = w << 16; return v.f;
}
static __device__ __forceinline__ float bf2f_hi(u32 w){
  union { u32 u; float f; } v; v.u = w & 0xffff0000u; return v.f;
}
static __device__ __forceinline__ float bf2f16(u16 h){
  union { u32 u; float f; } v; v.u = ((u32)h) << 16; return v.f;
}
static __device__ __forceinline__ u32 pk2(float a, float b){
  return (u32)f2bf(a) | (((u32)f2bf(b)) << 16);
}

// ---------- xt: transpose x -> xtb bf16 | tails: W->bf16 + stat zero + cntR zero ----------
// grid MUST be NBLK + 8 blocks x 256
__global__ __launch_bounds__(256) void k_xt(const float* __restrict__ x, u16* __restrict__ xtb,
    const float* __restrict__ W1, const float* __restrict__ W2,
    u16* __restrict__ w1b, u16* __restrict__ w2b, float* __restrict__ stat,
    int* __restrict__ cntR)
{
  __shared__ float tile[32][257];
  if (blockIdx.x >= NBLK){
    int b3 = blockIdx.x - NBLK;
    if (b3 == 0 && threadIdx.x < 64) stat[threadIdx.x] = 0.f;
    const int T1 = 128*64, T2 = T1 + 128*128;
    for (int i = b3*256 + threadIdx.x; i < T2; i += 8*256){
      if (i < T1) w1b[i] = f2bf(W1[i]);
      else { int j = i - T1; w2b[j] = f2bf(W2[j]); }
    }
    // zero the 8 replica counters (3.2 MB)
    int4 z = {0,0,0,0};
    int4* c4 = (int4*)cntR;
    const int NC4 = (8*NVP*4)/16;   // 200192
    for (int q = b3*256 + threadIdx.x; q < NC4; q += 8*256) c4[q] = z;
    return;
  }
  int t = threadIdx.x;
  int v0 = blockIdx.x*256;
  #pragma unroll
  for (int r = 0; r < 32; r++){
    int v = v0 + t;
    tile[r][t] = (v < NV) ? x[(size_t)r*NV + v] : 0.f;
  }
  __syncthreads();
  int v = v0 + t;
  if (v < NV){
    u16 o[32] __attribute__((aligned(16)));
    #pragma unroll
    for (int r = 0; r < 32; r++) o[r] = f2bf(tile[r][t]);
    uint4* dst = (uint4*)(xtb + (size_t)v*32);
    #pragma unroll
    for (int k = 0; k < 4; k++) dst[k] = *(uint4*)(o + k*8);
  }
}

// ---------- slot: ONE atomic pass, XCD-replicated counters ----------
// grid MUST be 1024 blocks x 256. Block b uses replica b&7.
__global__ __launch_bounds__(256) void k_slot(const int* __restrict__ elem,
    int* __restrict__ cntR, int* __restrict__ slot)
{
  int b = blockIdx.x;
  int* myc = cntR + (b & 7)*NVP;
  int i0 = b*768 + threadIdx.x;
  #pragma unroll
  for (int k = 0; k < 3; k++){
    int i = i0 + k*256;
    int v = elem[i];
    slot[i] = atomicAdd(myc + v, 1);
  }
}

// ---------- scan stage A: per-block raw sums over the 8 replicas ----------
__global__ __launch_bounds__(256) void k_scan_a(const int* __restrict__ cntR, int* __restrict__ bsum)
{
  int v = blockIdx.x*256 + threadIdx.x;
  int x = 0;
  if (v < NV){
    #pragma unroll
    for (int r = 0; r < 8; r++) x += cntR[r*NVP + v];
  }
  #pragma unroll
  for (int off = 32; off > 0; off >>= 1) x += __shfl_down(x, off);
  __shared__ int ls[4];
  int wid = threadIdx.x >> 6, lane = threadIdx.x & 63;
  if (lane == 0) ls[wid] = x;
  __syncthreads();
  if (threadIdx.x == 0) bsum[blockIdx.x] = ls[0] + ls[1] + ls[2] + ls[3];
}

// ---------- scan stage C: rows + per-replica bases ----------
__global__ __launch_bounds__(256) void k_scan_c(const int* __restrict__ cntR,
    const int* __restrict__ bsum, int* __restrict__ rows, int* __restrict__ baseR)
{
  int wid = threadIdx.x >> 6, lane = threadIdx.x & 63;
  int v = blockIdx.x*256 + threadIdx.x;
  int cr[8];
  #pragma unroll
  for (int r = 0; r < 8; r++) cr[r] = (v < NV) ? cntR[r*NVP + v] : 0;
  int pre[8]; int x = 0;
  #pragma unroll
  for (int r = 0; r < 8; r++){ pre[r] = x; x += cr[r]; }
  int incl = x;
  #pragma unroll
  for (int off = 1; off <= 32; off <<= 1){
    int y = __shfl_up(incl, off);
    if (lane >= off) incl += y;
  }
  __shared__ int wt[4];
  __shared__ int sbase;
  if (lane == 63) wt[wid] = incl;
  if (threadIdx.x < 64){
    int s = 0;
    for (int i = threadIdx.x; i < blockIdx.x; i += 64) s += bsum[i];
    #pragma unroll
    for (int off = 32; off > 0; off >>= 1) s += __shfl_down(s, off);
    if (threadIdx.x == 0) sbase = s;
  }
  __syncthreads();
  int woff = 0;
  for (int w = 0; w < 4; w++) if (w < wid) woff += wt[w];
  if (v < NV){
    int row0 = sbase + woff + incl - x;
    rows[v] = row0;
    #pragma unroll
    for (int r = 0; r < 8; r++) baseR[r*NVP + v] = row0 + pre[r];
  }
}

// ---------- pos2: streaming pos[i] = baseR[r(i)][elem[i]] + slot[i], in-place ----------
// grid MUST be 768 blocks x 256
__global__ __launch_bounds__(256) void k_pos2(const int* __restrict__ elem,
    const int* __restrict__ baseR, int* __restrict__ pos)
{
  int i4 = blockIdx.x*256 + threadIdx.x;
  int4 e = ((const int4*)elem)[i4];
  int4 s = ((const int4*)pos)[i4];
  int r = ((i4*4)/768) & 7;
  const int* br = baseR + r*NVP;
  int4 p;
  p.x = br[e.x] + s.x;
  p.y = br[e.y] + s.y;
  p.z = br[e.z] + s.z;
  p.w = br[e.w] + s.w;
  ((int4*)pos)[i4] = p;
}

// ---------- conv1: one-shot, 2 groups/wave straight-line, W1 in regs ----------
// grid MUST be 3072 blocks x 256 (12288 waves; ngrp = 24576)
__global__ __launch_bounds__(256) void k_conv1(const int* __restrict__ elem,
    const u16* __restrict__ xtb, const u16* __restrict__ w1b,
    const float* __restrict__ b1, const int* __restrict__ pos, u16* __restrict__ hbuf)
{
  const int lane = threadIdx.x & 63;
  const int col = lane & 15, kg = lane >> 4, b = lane & 3;
  s16x8 wf[8][2];
  #pragma unroll
  for (int j2 = 0; j2 < 8; j2++)
    #pragma unroll
    for (int t = 0; t < 2; t++)
      wf[j2][t] = *(const s16x8*)(w1b + (j2*16 + col)*64 + t*32 + kg*8);
  float bb[8];
  #pragma unroll
  for (int j2 = 0; j2 < 8; j2++) bb[j2] = b1[j2*16 + col];

  int wave = (int)((blockIdx.x*blockDim.x + threadIdx.x) >> 6);
  int g0 = wave, g1 = wave + 12288;
  int ma0 = g0*4 + (col >> 2), ma1 = g1*4 + (col >> 2);
  int me0 = g0*4 + kg,         me1 = g1*4 + kg;

  int e00 = elem[ma0*8 + kg], e01 = elem[ma0*8 + 4 + kg];
  int e10 = elem[ma1*8 + kg], e11 = elem[ma1*8 + 4 + kg];
  int4 p0l = *(const int4*)(pos + me0*8), p0h = *(const int4*)(pos + me0*8 + 4);
  int4 p1l = *(const int4*)(pos + me1*8), p1h = *(const int4*)(pos + me1*8 + 4);
  s16x8 a00 = *(const s16x8*)(xtb + (size_t)e00*32 + b*8);
  s16x8 a01 = *(const s16x8*)(xtb + (size_t)e01*32 + b*8);
  s16x8 a10 = *(const s16x8*)(xtb + (size_t)e10*32 + b*8);
  s16x8 a11 = *(const s16x8*)(xtb + (size_t)e11*32 + b*8);

  int pe0[8] = {p0l.x,p0l.y,p0l.z,p0l.w,p0h.x,p0h.y,p0h.z,p0h.w};
  int pe1[8] = {p1l.x,p1l.y,p1l.z,p1l.w,p1h.x,p1h.y,p1h.z,p1h.w};

  #pragma unroll
  for (int j2 = 0; j2 < 8; j2++){
    f32x4 c = {0.f,0.f,0.f,0.f};
    c = __builtin_amdgcn_mfma_f32_16x16x32_bf16(a00, wf[j2][0], c, 0, 0, 0);
    c = __builtin_amdgcn_mfma_f32_16x16x32_bf16(a01, wf[j2][1], c, 0, 0, 0);
    uint2 d; d.x = pk2(c[0]+bb[j2], c[1]+bb[j2]); d.y = pk2(c[2]+bb[j2], c[3]+bb[j2]);
    *(uint2*)(hbuf + (size_t)pe0[j2]*64 + col*4) = d;
  }
  #pragma unroll
  for (int j2 = 0; j2 < 8; j2++){
    f32x4 c = {0.f,0.f,0.f,0.f};
    c = __builtin_amdgcn_mfma_f32_16x16x32_bf16(a10, wf[j2][0], c, 0, 0, 0);
    c = __builtin_amdgcn_mfma_f32_16x16x32_bf16(a11, wf[j2][1], c, 0, 0, 0);
    uint2 d; d.x = pk2(c[0]+bb[j2], c[1]+bb[j2]); d.y = pk2(c[2]+bb[j2], c[3]+bb[j2]);
    *(uint2*)(hbuf + (size_t)pe1[j2]*64 + col*4) = d;
  }
}

// ---------- conv2: mbuf gather + BN1+relu inline, W2 in LDS ----------
// grid MUST be 3072 blocks x 256
__global__ __launch_bounds__(256) void k_conv2(const int* __restrict__ elem,
    const u16* __restrict__ mbuf, const u16* __restrict__ w2b,
    const float* __restrict__ b2, const float* __restrict__ stat,
    const float* __restrict__ gamma, const float* __restrict__ beta,
    const int* __restrict__ pos, u16* __restrict__ hbuf)
{
  __shared__ u16 wl[16384];   // 32 frags x 64 lanes x 8 bf16, chunk (j2*4+t)*64+lane
  __shared__ float sc[16], sh[16];
  #pragma unroll
  for (int r = 0; r < 8; r++){
    int q = threadIdx.x + 256*r;
    int j2t = q >> 6, ln = q & 63;
    int cc = ln & 15, kk = ln >> 4;
    int j2 = j2t >> 2, tt = j2t & 3;
    *(s16x8*)(wl + (size_t)q*8) =
        *(const s16x8*)(w2b + (j2*16 + cc)*128 + tt*32 + kk*8);
  }
  if (threadIdx.x < 16){
    int co = threadIdx.x;
    const float invn = 1.0f / (float)(NB*NV);
    float m = stat[co]*invn;
    float var = stat[16+co]*invn - m*m;
    float s = gamma[co]*rsqrtf(var + 1e-5f);
    sc[co] = s; sh[co] = beta[co] - m*s;
  }

  const int lane = threadIdx.x & 63;
  const int col = lane & 15, kg = lane >> 4, b = lane & 3;
  const int p = kg >> 1;            // slot parity
  const int c0 = (kg & 1)*8;        // channel offset
  float bb[8];
  #pragma unroll
  for (int j2 = 0; j2 < 8; j2++) bb[j2] = b2[j2*16 + col];

  int wave = (int)((blockIdx.x*blockDim.x + threadIdx.x) >> 6);
  int g0 = wave, g1 = wave + 12288;
  int ma0 = g0*4 + (col >> 2), ma1 = g1*4 + (col >> 2);
  int me0 = g0*4 + kg,         me1 = g1*4 + kg;

  int4 e0l = *(const int4*)(elem + ma0*8), e0h = *(const int4*)(elem + ma0*8 + 4);
  int4 e1l = *(const int4*)(elem + ma1*8), e1h = *(const int4*)(elem + ma1*8 + 4);
  int4 p0l = *(const int4*)(pos + me0*8),  p0h = *(const int4*)(pos + me0*8 + 4);
  int4 p1l = *(const int4*)(pos + me1*8),  p1h = *(const int4*)(pos + me1*8 + 4);

  int v00 = p ? e0l.y : e0l.x, v01 = p ? e0l.w : e0l.z;
  int v02 = p ? e0h.y : e0h.x, v03 = p ? e0h.w : e0h.z;
  int v10 = p ? e1l.y : e1l.x, v11 = p ? e1l.w : e1l.z;
  int v12 = p ? e1h.y : e1h.x, v13 = p ? e1h.w : e1h.z;

  s16x8 af0[4], af1[4];
  af0[0] = *(const s16x8*)(mbuf + (size_t)v00*64 + b*16 + c0);
  af0[1] = *(const s16x8*)(mbuf + (size_t)v01*64 + b*16 + c0);
  af0[2] = *(const s16x8*)(mbuf + (size_t)v02*64 + b*16 + c0);
  af0[3] = *(const s16x8*)(mbuf + (size_t)v03*64 + b*16 + c0);
  af1[0] = *(const s16x8*)(mbuf + (size_t)v10*64 + b*16 + c0);
  af1[1] = *(const s16x8*)(mbuf + (size_t)v11*64 + b*16 + c0);
  af1[2] = *(const s16x8*)(mbuf + (size_t)v12*64 + b*16 + c0);
  af1[3] = *(const s16x8*)(mbuf + (size_t)v13*64 + b*16 + c0);

  int pe0[8] = {p0l.x,p0l.y,p0l.z,p0l.w,p0h.x,p0h.y,p0h.z,p0h.w};
  int pe1[8] = {p1l.x,p1l.y,p1l.z,p1l.w,p1h.x,p1h.y,p1h.z,p1h.w};

  __syncthreads();   // wl + sc/sh visible

  // BN1 + relu on gathered fragments (identical arithmetic to old k_apply1)
  #pragma unroll
  for (int t = 0; t < 4; t++){
    u32 r0[4], r1[4];
    #pragma unroll
    for (int ii = 0; ii < 4; ii++){
      int ca = c0 + 2*ii, cb = ca + 1;
      float x0 = bf2f16((u16)af0[t][2*ii])   * sc[ca] + sh[ca];
      float x1 = bf2f16((u16)af0[t][2*ii+1]) * sc[cb] + sh[cb];
      float y0 = bf2f16((u16)af1[t][2*ii])   * sc[ca] + sh[ca];
      float y1 = bf2f16((u16)af1[t][2*ii+1]) * sc[cb] + sh[cb];
      r0[ii] = pk2(fmaxf(x0, 0.f), fmaxf(x1, 0.f));
      r1[ii] = pk2(fmaxf(y0, 0.f), fmaxf(y1, 0.f));
    }
    af0[t] = *(s16x8*)r0;
    af1[t] = *(s16x8*)r1;
  }

  #pragma unroll
  for (int j2 = 0; j2 < 8; j2++){
    s16x8 w0 = *(const s16x8*)(wl + ((size_t)(j2*4 + 0)*64 + lane)*8);
    s16x8 w1 = *(const s16x8*)(wl + ((size_t)(j2*4 + 1)*64 + lane)*8);
    s16x8 w2 = *(const s16x8*)(wl + ((size_t)(j2*4 + 2)*64 + lane)*8);
    s16x8 w3 = *(const s16x8*)(wl + ((size_t)(j2*4 + 3)*64 + lane)*8);
    f32x4 c = {0.f,0.f,0.f,0.f};
    c = __builtin_amdgcn_mfma_f32_16x16x32_bf16(af0[0], w0, c, 0, 0, 0);
    c = __builtin_amdgcn_mfma_f32_16x16x32_bf16(af0[1], w1, c, 0, 0, 0);
    c = __builtin_amdgcn_mfma_f32_16x16x32_bf16(af0[2], w2, c, 0, 0, 0);
    c = __builtin_amdgcn_mfma_f32_16x16x32_bf16(af0[3], w3, c, 0, 0, 0);
    uint2 d; d.x = pk2(c[0]+bb[j2], c[1]+bb[j2]); d.y = pk2(c[2]+bb[j2], c[3]+bb[j2]);
    *(uint2*)(hbuf + (size_t)pe0[j2]*64 + col*4) = d;
  }
  #pragma unroll
  for (int j2 = 0; j2 < 8; j2++){
    s16x8 w0 = *(const s16x8*)(wl + ((size_t)(j2*4 + 0)*64 + lane)*8);
    s16x8 w1 = *(const s16x8*)(wl + ((size_t)(j2*4 + 1)*64 + lane)*8);
    s16x8 w2 = *(const s16x8*)(wl + ((size_t)(j2*4 + 2)*64 + lane)*8);
    s16x8 w3 = *(const s16x8*)(wl + ((size_t)(j2*4 + 3)*64 + lane)*8);
    f32x4 c = {0.f,0.f,0.f,0.f};
    c = __builtin_amdgcn_mfma_f32_16x16x32_bf16(af1[0], w0, c, 0, 0, 0);
    c = __builtin_amdgcn_mfma_f32_16x16x32_bf16(af1[1], w1, c, 0, 0, 0);
    c = __builtin_amdgcn_mfma_f32_16x16x32_bf16(af1[2], w2, c, 0, 0, 0);
    c = __builtin_amdgcn_mfma_f32_16x16x32_bf16(af1[3], w3, c, 0, 0, 0);
    uint2 d; d.x = pk2(c[0]+bb[j2], c[1]+bb[j2]); d.y = pk2(c[2]+bb[j2], c[3]+bb[j2]);
    *(uint2*)(hbuf + (size_t)pe1[j2]*64 + col*4) = d;
  }
}

// ---------- segmented reduce: 3 upfront row-groups (covers cnt<=12), half-wave/vertex ----------
// grid MUST be REDB blocks x 256
__global__ __launch_bounds__(256) void k_reduce(const u16* __restrict__ hbuf,
    const int* __restrict__ rows, u16* __restrict__ mbuf, float* __restrict__ stat)
{
  int lane = threadIdx.x & 63, wid = threadIdx.x >> 6;
  int half = lane >> 5;
  int hl   = lane & 31;
  int k8   = lane & 7;
  int rg   = (lane >> 3) & 3;
  int w = (blockIdx.x*blockDim.x + threadIdx.x) >> 6;
  int v0 = w * VPW;

  int vv = v0 + lane;
  int rr = 0;
  if (lane < VPW + 1) rr = (vv < NV) ? rows[vv] : NPOS;

  int rs[7], ce[7];
  #pragma unroll
  for (int j = 0; j < 7; j++){
    rs[j] = __shfl(rr, 2*j + half);
    ce[j] = __shfl(rr, 2*j + half + 1) - rs[j];
  }

  uint4 d0[7], d1[7], d2[7];
  #pragma unroll
  for (int j = 0; j < 7; j++){
    uint4 z = {0u,0u,0u,0u};
    d0[j] = z; d1[j] = z; d2[j] = z;
    const u16* base = hbuf + (size_t)rs[j]*64 + hl*8;
    if (rg     < ce[j]) d0[j] = *(const uint4*)(base);
    if (4 + rg < ce[j]) d1[j] = *(const uint4*)(base + 4*64);
    if (8 + rg < ce[j]) d2[j] = *(const uint4*)(base + 8*64);
  }

  float st_s0 = 0.f, st_q0 = 0.f, st_s1 = 0.f, st_q1 = 0.f;

  #pragma unroll
  for (int j = 0; j < 7; j++){
    float a0,a1,a2,a3,a4,a5,a6,a7;
    {
      uint4 dA = d0[j], dB = d1[j], dC = d2[j];
      a0 = bf2f_lo(dA.x)+bf2f_lo(dB.x)+bf2f_lo(dC.x);
      a1 = bf2f_hi(dA.x)+bf2f_hi(dB.x)+bf2f_hi(dC.x);
      a2 = bf2f_lo(dA.y)+bf2f_lo(dB.y)+bf2f_lo(dC.y);
      a3 = bf2f_hi(dA.y)+bf2f_hi(dB.y)+bf2f_hi(dC.y);
      a4 = bf2f_lo(dA.z)+bf2f_lo(dB.z)+bf2f_lo(dC.z);
      a5 = bf2f_hi(dA.z)+bf2f_hi(dB.z)+bf2f_hi(dC.z);
      a6 = bf2f_lo(dA.w)+bf2f_lo(dB.w)+bf2f_lo(dC.w);
      a7 = bf2f_hi(dA.w)+bf2f_hi(dB.w)+bf2f_hi(dC.w);
    }
    for (int p = 12; p < ce[j]; p += 4){
      uint4 d = {0u,0u,0u,0u};
      if (p + rg < ce[j]) d = *(const uint4*)(hbuf + (size_t)(rs[j]+p)*64 + hl*8);
      a0 += bf2f_lo(d.x); a1 += bf2f_hi(d.x); a2 += bf2f_lo(d.y); a3 += bf2f_hi(d.y);
      a4 += bf2f_lo(d.z); a5 += bf2f_hi(d.z); a6 += bf2f_lo(d.w); a7 += bf2f_hi(d.w);
    }
    #pragma unroll
    for (int off = 8; off <= 16; off <<= 1){
      a0 += __shfl_xor(a0, off); a1 += __shfl_xor(a1, off);
      a2 += __shfl_xor(a2, off); a3 += __shfl_xor(a3, off);
      a4 += __shfl_xor(a4, off); a5 += __shfl_xor(a5, off);
      a6 += __shfl_xor(a6, off); a7 += __shfl_xor(a7, off);
    }
    int v = v0 + 2*j + half;
    if (hl < 8 && v < NV){
      float inv = 1.0f / fmaxf((float)ce[j], 1.0f);
      float c0b[4] = {a0*inv, a1*inv, a2*inv, a3*inv};
      float c1b[4] = {a4*inv, a5*inv, a6*inv, a7*inv};
      #pragma unroll
      for (int q = 0; q < 4; q++){
        *(u32*)(mbuf + (size_t)v*64 + q*16 + 2*k8) = pk2(c0b[q], c1b[q]);
        st_s0 += c0b[q]; st_q0 += c0b[q]*c0b[q];
        st_s1 += c1b[q]; st_q1 += c1b[q]*c1b[q];
      }
    }
  }

  st_s0 += __shfl_xor(st_s0, 32); st_q0 += __shfl_xor(st_q0, 32);
  st_s1 += __shfl_xor(st_s1, 32); st_q1 += __shfl_xor(st_q1, 32);
  __shared__ float ls[4][16], lq[4][16];
  if (lane < 8){
    ls[wid][2*k8] = st_s0; ls[wid][2*k8+1] = st_s1;
    lq[wid][2*k8] = st_q0; lq[wid][2*k8+1] = st_q1;
  }
  __syncthreads();
  if (threadIdx.x < 32){
    int c2 = threadIdx.x & 15, which = threadIdx.x >> 4;
    float tot = 0.f;
    #pragma unroll
    for (int w2 = 0; w2 < 4; w2++) tot += which ? lq[w2][c2] : ls[w2][c2];
    unsafeAtomicAdd(stat + which*16 + c2, tot);
  }
}

// ---------- final: BN2 (inline finalize) + skip GEMV + relu + transpose ----------
__global__ __launch_bounds__(256) void k_final(const u16* __restrict__ mbuf,
    const float* __restrict__ stat, const float* __restrict__ gamma,
    const float* __restrict__ beta, const float* __restrict__ x,
    const float* __restrict__ wsk, const float* __restrict__ bsk, float* __restrict__ out)
{
  __shared__ float sc[16], sh[16];
  if (threadIdx.x < 16){
    int co = threadIdx.x;
    const float invn = 1.0f / (float)(NB*NV);
    float m = stat[co]*invn;
    float var = stat[16+co]*invn - m*m;
    float s = gamma[co]*rsqrtf(var + 1e-5f);
    sc[co] = s; sh[co] = beta[co] - m*s + bsk[co];
  }
  __syncthreads();
  int n = blockIdx.x*blockDim.x + threadIdx.x;
  int b = blockIdx.y;
  if (n >= NV) return;
  float xv[8];
  #pragma unroll
  for (int c = 0; c < 8; c++) xv[c] = x[((size_t)b*8 + c)*NV + n];
  const uint4* src = (const uint4*)(mbuf + (size_t)n*64 + b*16);
  uint4 m0 = src[0], m1 = src[1];
  u32 mw[8] = {m0.x,m0.y,m0.z,m0.w,m1.x,m1.y,m1.z,m1.w};
  #pragma unroll
  for (int k = 0; k < 8; k++){
    #pragma unroll
    for (int h = 0; h < 2; h++){
      int co = 2*k + h;
      float val = (h ? bf2f_hi(mw[k]) : bf2f_lo(mw[k]))*sc[co] + sh[co];
      #pragma unroll
      for (int c = 0; c < 8; c++) val += wsk[co*8+c]*xv[c];
      out[((size_t)b*16 + co)*NV + n] = fmaxf(val, 0.f);
    }
  }
}

extern "C" void kernel_launch(void* const* d_in, const int* in_sizes, int n_in,
                              void* d_out, int out_size, void* d_ws, size_t ws_size,
                              hipStream_t stream) {
  const float* x    = (const float*)d_in[0];
  const int*   elem = (const int*)  d_in[1];
  const float* W1   = (const float*)d_in[2];
  const float* b1   = (const float*)d_in[3];
  const float* g1   = (const float*)d_in[4];
  const float* be1  = (const float*)d_in[5];
  const float* W2   = (const float*)d_in[6];
  const float* b2   = (const float*)d_in[7];
  const float* g2   = (const float*)d_in[8];
  const float* be2  = (const float*)d_in[9];
  const float* Wsk  = (const float*)d_in[10];
  const float* bsk  = (const float*)d_in[11];
  float* out = (float*)d_out;

  if (ws_size < (size_t)WS_NEED) return;  // visible failure rather than corruption

  char* ws = (char*)d_ws;
  float* stat  = (float*)(ws + OFF_STAT);   // [0..31] BN1, [32..63] BN2
  int*   rows  = (int*)  (ws + OFF_ROWS);
  int*   bsum  = (int*)  (ws + OFF_BSUM);
  int*   pos   = (int*)  (ws + OFF_POS);    // slot then pos (in-place)
  u16*   xtb   = (u16*)  (ws + OFF_XTB);
  u16*   w1b   = (u16*)  (ws + OFF_W1B);
  u16*   w2b   = (u16*)  (ws + OFF_W2B);
  u16*   mbuf  = (u16*)  (ws + OFF_MBUF);
  u16*   hbuf  = (u16*)  (ws + OFF_HBUF);
  int*   cntR  = (int*)  (ws + OFF_CNTR);
  int*   baseR = (int*)  (ws + OFF_BASER);

  k_xt<<<NBLK + 8, 256, 0, stream>>>(x, xtb, W1, W2, w1b, w2b, stat, cntR);
  k_slot<<<1024, 256, 0, stream>>>(elem, cntR, pos);
  k_scan_a<<<NBLK, 256, 0, stream>>>(cntR, bsum);
  k_scan_c<<<NBLK, 256, 0, stream>>>(cntR, bsum, rows, baseR);
  k_pos2<<<768, 256, 0, stream>>>(elem, baseR, pos);

  k_conv1<<<3072, 256, 0, stream>>>(elem, xtb, w1b, b1, pos, hbuf);
  k_reduce<<<REDB, 256, 0, stream>>>(hbuf, rows, mbuf, stat);

  k_conv2<<<3072, 256, 0, stream>>>(elem, mbuf, w2b, b2, stat, g1, be1, pos, hbuf);
  k_reduce<<<REDB, 256, 0, stream>>>(hbuf, rows, mbuf, stat + 32);
  k_final<<<dim3((NV+255)/256, NB), 256, 0, stream>>>(mbuf, stat + 32, g2, be2, x, Wsk, bsk, out);
}